// Round 12
// baseline (182.346 us; speedup 1.0000x reference)
//
#include <hip/hip_runtime.h>
#include <hip/hip_bf16.h>

typedef unsigned int u32;
typedef unsigned short u16;

#define B_   32
#define S_   512
#define H_   256
#define NH_  8
#define HD_  32

typedef __attribute__((ext_vector_type(8))) short short8;
typedef __attribute__((ext_vector_type(4))) float f32x4;

// ---------- bf16 helpers (fast RNE, finite inputs only) ----------
__device__ __forceinline__ u32   fbits(float f){ union{float f;u32 u;} c; c.f=f; return c.u; }
__device__ __forceinline__ float bfl(u32 u){ union{u32 i;float f;} c; c.i = u << 16;          return c.f; }
__device__ __forceinline__ float bfh(u32 u){ union{u32 i;float f;} c; c.i = u & 0xffff0000u;  return c.f; }
__device__ __forceinline__ float bf1(u16 u){ union{u32 i;float f;} c; c.i = ((u32)u) << 16;   return c.f; }
__device__ __forceinline__ u16   f2b(float f){ const u32 u = fbits(f); return (u16)((u + 0x7fffu + ((u >> 16) & 1u)) >> 16); }
__device__ __forceinline__ u32   pk2(float a, float b){
  const u32 ua = fbits(a), ub = fbits(b);
  const u32 ra = (ua + 0x7fffu + ((ua >> 16) & 1u)) >> 16;
  const u32 rb = (ub + 0x7fffu + ((ub >> 16) & 1u)) & 0xffff0000u;
  return ra | rb;
}
__device__ __forceinline__ void  unp8(const uint4 u, float* f){
  f[0]=bfl(u.x); f[1]=bfh(u.x); f[2]=bfl(u.y); f[3]=bfh(u.y);
  f[4]=bfl(u.z); f[5]=bfh(u.z); f[6]=bfl(u.w); f[7]=bfh(u.w);
}
__device__ __forceinline__ f32x4 mfma16(short8 a, short8 b, f32x4 c){
  return __builtin_amdgcn_mfma_f32_16x16x32_bf16(a, b, c, 0, 0, 0);
}

// ---------- dtype-polymorphic loads/stores ----------
template<int F32>
__device__ __forceinline__ void load8(const void* p, int e8, float* f) {
  if (F32) {
    const float4* q = (const float4*)p;
    const float4 a = q[e8 * 2], b = q[e8 * 2 + 1];
    f[0]=a.x; f[1]=a.y; f[2]=a.z; f[3]=a.w; f[4]=b.x; f[5]=b.y; f[6]=b.z; f[7]=b.w;
  } else {
    unp8(((const uint4*)p)[e8], f);
  }
}
template<int F32>
__device__ __forceinline__ void store8(void* p, int e8, const float* f) {
  if (F32) {
    float4* q = (float4*)p;
    q[e8 * 2]     = make_float4(f[0], f[1], f[2], f[3]);
    q[e8 * 2 + 1] = make_float4(f[4], f[5], f[6], f[7]);
  } else {
    uint4 u;
    u.x = pk2(f[0], f[1]); u.y = pk2(f[2], f[3]);
    u.z = pk2(f[4], f[5]); u.w = pk2(f[6], f[7]);
    ((uint4*)p)[e8] = u;
  }
}
template<int F32>
__device__ __forceinline__ float load1(const void* p, size_t e) {
  return F32 ? ((const float*)p)[e] : bf1(((const u16*)p)[e]);
}
template<int F32>
__device__ __forceinline__ short8 loadBfrag(const void* wp, int row, int k0, int K) {
  if (F32) {
    const float* w = (const float*)wp + (size_t)row * K + k0;
    const float4 a = *(const float4*)w;
    const float4 b = *(const float4*)(w + 4);
    union { u32 u[4]; short8 s; } r;
    r.u[0] = pk2(a.x, a.y); r.u[1] = pk2(a.z, a.w);
    r.u[2] = pk2(b.x, b.y); r.u[3] = pk2(b.z, b.w);
    return r.s;
  } else {
    return *(const short8*)((const u16*)wp + (size_t)row * K + k0);
  }
}

// ---------- dtype sniff (first 4KB of `inputs`), one atomic per wave ----------
__device__ __forceinline__ int sniff_mode(const void* xin) {   // 0=bf16, 1=f32
  __shared__ int votes;
  const int tid = threadIdx.x;
  if (tid == 0) votes = 0;
  __syncthreads();
  const u32* xw = (const u32*)xin;
  int h = 0;
#pragma unroll
  for (int j = 0; j < 4; ++j) {
    const u32 u = xw[(tid << 2) + j];
    const u32 e = (u >> 7) & 0xFF;
    h += (e >= 100 && e <= 135) ? 1 : 0;
  }
  const unsigned long long m = __ballot(h >= 3);
  if ((tid & 63) == 0) atomicAdd(&votes, __popcll(m));
  __syncthreads();
  return (votes >= 128) ? 0 : 1;
}

// ============================================================
// LN + QKV body. Grid 512 = 32 rows/block, ALL 768 outputs/block
// (12 n-tiles/wave). LN computed exactly once per row chip-wide.
// A-frags (2 m-tiles) register-resident; constant-index B-frag dbuf.
// ============================================================
template<int F32>
__device__ __forceinline__ void ln_body(
    const void* __restrict__ xin, const void* __restrict__ rmask,
    const void* __restrict__ wi, const void* __restrict__ gamma,
    const void* __restrict__ beta,
    u16* __restrict__ qbuf, u16* __restrict__ kbuf, u16* __restrict__ vt,
    u16* XnF, float* lmr)
{
  const int tid = threadIdx.x;
  const int l = tid & 63, w = tid >> 6;
  const int lr = l & 15, quad = l >> 4;
  const int row0 = blockIdx.x * 32;

  // ---- Phase A: LayerNorm for 32 rows, frag-major store ----
  {
    const int r = tid >> 5, ln = tid & 31;
    float g[8], bb[8];
    load8<F32>(gamma, ln, g);
    load8<F32>(beta,  ln, bb);
    const int c = ln >> 2, qd = ln & 3;
#pragma unroll
    for (int p = 0; p < 4; ++p) {
      const int R = p * 8 + r;                 // local row 0..31
      const int grow = row0 + R;
      float x[8]; load8<F32>(xin, grow * 32 + ln, x);
      float s = 0.f, sq = 0.f;
#pragma unroll
      for (int j = 0; j < 8; ++j) { s += x[j]; sq += x[j] * x[j]; }
#pragma unroll
      for (int m = 1; m < 32; m <<= 1) { s += __shfl_xor(s, m); sq += __shfl_xor(sq, m); }
      const float mu  = s * (1.f / 256.f);
      const float var = sq * (1.f / 256.f) - mu * mu;
      const float rs  = rsqrtf(var + 1e-5f);
      union { u32 u[4]; short8 s8; } pk;
#pragma unroll
      for (int j = 0; j < 4; ++j)
        pk.u[j] = pk2((x[2*j] - mu) * rs * g[2*j] + bb[2*j],
                      (x[2*j+1] - mu) * rs * g[2*j+1] + bb[2*j+1]);
      const int t = R >> 4, rm = R & 15;
      *(short8*)(XnF + (((t * 8 + c) * 64 + qd * 16 + rm) << 3)) = pk.s8;
      if (ln == 0) lmr[R] = logf(load1<F32>(rmask, grow));
    }
  }
  __syncthreads();

  // ---- A-fragments -> registers (2 m-tiles, once) ----
  short8 Af[2][8];
#pragma unroll
  for (int mt = 0; mt < 2; ++mt)
#pragma unroll
    for (int c = 0; c < 8; ++c)
      Af[mt][c] = *(const short8*)(XnF + (((mt * 8 + c) * 64 + l) << 3));

  const int bb_ = row0 >> 9;
  const int sB  = row0 & 511;
  const int c16 = sB >> 5;                 // 32-key chunk (constant per block)
  const int tbase = w * 12;

  short8 Bf[2][8];
#pragma unroll
  for (int c = 0; c < 8; ++c)
    Bf[0][c] = loadBfrag<F32>(wi, tbase * 16 + lr, c * 32 + quad * 8, 256);

#pragma unroll
  for (int nt = 0; nt < 12; ++nt) {
    const int cb = nt & 1;
    if (nt < 11) {
#pragma unroll
      for (int c = 0; c < 8; ++c)
        Bf[cb ^ 1][c] = loadBfrag<F32>(wi, (tbase + nt + 1) * 16 + lr, c * 32 + quad * 8, 256);
    }

    f32x4 a[2];
    a[0] = (f32x4){0.f, 0.f, 0.f, 0.f};
    a[1] = (f32x4){0.f, 0.f, 0.f, 0.f};
#pragma unroll
    for (int c = 0; c < 8; ++c) {
      a[0] = mfma16(Af[0][c], Bf[cb][c], a[0]);
      a[1] = mfma16(Af[1][c], Bf[cb][c], a[1]);
    }

    const int nAbs  = (tbase + nt) * 16;
    const int type  = nAbs >> 8;              // 0=q 1=k 2=v
    const int dbase = nAbs & 255;
    if (type < 2) {
      const int d  = dbase + lr;
      const int h  = d >> 5, dd = d & 31;
      const int bh = bb_ * NH_ + h;
      u16* dst = (type == 0) ? qbuf : kbuf;
#pragma unroll
      for (int mt = 0; mt < 2; ++mt) {
        const int sL = mt * 16 + quad * 4;
#pragma unroll
        for (int i = 0; i < 4; ++i) {
          float v = a[mt][i];
          v = (type == 0) ? (v * v + 1e-6f) : (v + lmr[sL + i]);
          dst[((size_t)bh * S_ + sB + sL + i) * HD_ + dd] = f2b(v);
        }
      }
    } else {
      const int dv  = dbase + lr;
      const int hv  = dv >> 5, ddv = dv & 31;
      const int bhv = bb_ * NH_ + hv;
#pragma unroll
      for (int mt = 0; mt < 2; ++mt) {
        const int slot16 = ((c16 * 2 + (ddv >> 4)) * 4 + quad) * 16 + (ddv & 15);
        uint2 pkv;
        pkv.x = pk2(a[mt][0], a[mt][1]);
        pkv.y = pk2(a[mt][2], a[mt][3]);
        *(uint2*)(vt + (size_t)bhv * (S_ * HD_) + slot16 * 8 + mt * 4) = pkv;
      }
    }
  }
}

__global__ __launch_bounds__(256, 2) void ln_qkv_mfma(
    const void* __restrict__ xin, const void* __restrict__ rmask,
    const void* __restrict__ wi, const void* __restrict__ gamma,
    const void* __restrict__ beta,
    u16* __restrict__ qbuf, u16* __restrict__ kbuf, u16* __restrict__ vt)
{
  __shared__ __align__(16) u16 XnF[2 * 8 * 64 * 8];   // 16 KB
  __shared__ float lmr[32];
  if (sniff_mode(xin) == 0) ln_body<0>(xin, rmask, wi, gamma, beta, qbuf, kbuf, vt, XnF, lmr);
  else                      ln_body<1>(xin, rmask, wi, gamma, beta, qbuf, kbuf, vt, XnF, lmr);
}

// ============================================================
// Kernel 2: LDS-free flash attention, online softmax, 2 q-tiles/wave.
// Grid 1024 = (sq 0..3)*256 + bh (XCD swizzle). V sigma-key-permuted.
// (unchanged from R11)
// ============================================================
__global__ __launch_bounds__(256, 3) void attn_mfma(
    const u16* __restrict__ qbuf, const u16* __restrict__ kbuf,
    const u16* __restrict__ vt, u16* __restrict__ ctx)
{
  __shared__ __align__(16) u16 OB[4][32 * 40];   // wave-private out transpose (10 KB)
  const int tid = threadIdx.x;
  const int bh = blockIdx.x & 255, sq = blockIdx.x >> 8;
  const int l = tid & 63, w = tid >> 6;
  const int lr = l & 15, quad = l >> 4;
  const size_t kvbase = (size_t)bh * (S_ * HD_);
  const int q0 = sq * 128 + w * 32;

  const float cE = 0.17677669529663688f * 1.4426950408889634f;

  const short8 qfA = *(const short8*)(qbuf + kvbase + (size_t)(q0 + lr) * HD_ + quad * 8);
  const short8 qfB = *(const short8*)(qbuf + kvbase + (size_t)(q0 + 16 + lr) * HD_ + quad * 8);
  const u16* kp = kbuf + kvbase + (size_t)lr * HD_ + quad * 8;
  const u16* vp = vt + kvbase;

  float mSA = -1e30f, lSA = 0.f, mSB = -1e30f, lSB = 0.f;
  f32x4 oA0 = {0.f,0.f,0.f,0.f}, oA1 = {0.f,0.f,0.f,0.f};
  f32x4 oB0 = {0.f,0.f,0.f,0.f}, oB1 = {0.f,0.f,0.f,0.f};

#pragma unroll
  for (int c = 0; c < 4; ++c) {
    f32x4 aA[8], aB[8];
#pragma unroll
    for (int j = 0; j < 8; ++j) {
      const short8 kf = *(const short8*)(kp + (c * 8 + j) * (16 * HD_));
      f32x4 z = {0.f,0.f,0.f,0.f};
      aA[j] = mfma16(kf, qfA, z);
      aB[j] = mfma16(kf, qfB, z);
    }

    float mcA = aA[0][0], mcB = aB[0][0];
#pragma unroll
    for (int j = 0; j < 8; ++j)
#pragma unroll
      for (int r = 0; r < 4; ++r) { mcA = fmaxf(mcA, aA[j][r]); mcB = fmaxf(mcB, aB[j][r]); }
    mcA = fmaxf(mcA, __shfl_xor(mcA, 16)); mcB = fmaxf(mcB, __shfl_xor(mcB, 16));
    mcA = fmaxf(mcA, __shfl_xor(mcA, 32)); mcB = fmaxf(mcB, __shfl_xor(mcB, 32));
    const float mNA = fmaxf(mSA, mcA * cE), mNB = fmaxf(mSB, mcB * cE);
    const float alA = exp2f(mSA - mNA),     alB = exp2f(mSB - mNB);
    float scA = 0.f, scB = 0.f;
#pragma unroll
    for (int j = 0; j < 8; ++j)
#pragma unroll
      for (int r = 0; r < 4; ++r) {
        const float pA = exp2f(fmaf(aA[j][r], cE, -mNA));
        const float pB = exp2f(fmaf(aB[j][r], cE, -mNB));
        aA[j][r] = pA; scA += pA;
        aB[j][r] = pB; scB += pB;
      }
    scA += __shfl_xor(scA, 16); scB += __shfl_xor(scB, 16);
    scA += __shfl_xor(scA, 32); scB += __shfl_xor(scB, 32);
    lSA = fmaf(lSA, alA, scA); mSA = mNA;
    lSB = fmaf(lSB, alB, scB); mSB = mNB;
#pragma unroll
    for (int r = 0; r < 4; ++r) {
      oA0[r] *= alA; oA1[r] *= alA;
      oB0[r] *= alB; oB1[r] *= alB;
    }

#pragma unroll
    for (int g = 0; g < 4; ++g) {
      const int c16 = c * 4 + g;
      const short8 v0 = *(const short8*)(vp + (((c16 * 8 +     quad) * 16 + lr) << 3));
      const short8 v1 = *(const short8*)(vp + (((c16 * 8 + 4 + quad) * 16 + lr) << 3));
      union { u32 u[4]; short8 s; } pa;
      pa.u[0] = pk2(aA[2*g][0],   aA[2*g][1]);
      pa.u[1] = pk2(aA[2*g][2],   aA[2*g][3]);
      pa.u[2] = pk2(aA[2*g+1][0], aA[2*g+1][1]);
      pa.u[3] = pk2(aA[2*g+1][2], aA[2*g+1][3]);
      oA0 = mfma16(pa.s, v0, oA0);
      oA1 = mfma16(pa.s, v1, oA1);
      pa.u[0] = pk2(aB[2*g][0],   aB[2*g][1]);
      pa.u[1] = pk2(aB[2*g][2],   aB[2*g][3]);
      pa.u[2] = pk2(aB[2*g+1][0], aB[2*g+1][1]);
      pa.u[3] = pk2(aB[2*g+1][2], aB[2*g+1][3]);
      oB0 = mfma16(pa.s, v0, oB0);
      oB1 = mfma16(pa.s, v1, oB1);
    }
  }
  const float invA = 1.f / lSA, invB = 1.f / lSB;

  u16* ob = OB[w];
#pragma unroll
  for (int r = 0; r < 4; ++r) {
    const int qq = quad * 4 + r;
    const float ivA = __shfl(invA, (l & 48) | qq);
    const float ivB = __shfl(invB, (l & 48) | qq);
    ob[qq * 40 + lr]             = f2b(oA0[r] * ivA);
    ob[qq * 40 + 16 + lr]        = f2b(oA1[r] * ivA);
    ob[(16 + qq) * 40 + lr]      = f2b(oB0[r] * ivB);
    ob[(16 + qq) * 40 + 16 + lr] = f2b(oB1[r] * ivB);
  }
#pragma unroll
  for (int t = 0; t < 2; ++t) {
    const int row = (l >> 2) + t * 16;
    const uint4 ov = *(const uint4*)(ob + row * 40 + (l & 3) * 8);
    *(uint4*)(ctx + kvbase + (size_t)(q0 + row) * HD_ + (l & 3) * 8) = ov;
  }
}

// ============================================================
// out-proj body (unchanged from R11).
// ============================================================
template<int F32>
__device__ __forceinline__ void proj_body(
    const u16* __restrict__ ctx, const void* __restrict__ xin,
    const void* __restrict__ wo, void* __restrict__ out,
    u16* XnF, u16* OutB)
{
  const int tid = threadIdx.x;
  const int l = tid & 63, w = tid >> 6;
  const int lr = l & 15, quad = l >> 4;
  const int row0 = blockIdx.x * 32;
  const int b = row0 >> 9, s0 = row0 & 511;

#pragma unroll
  for (int it = 0; it < 4; ++it) {
    const int idx = it * 256 + tid;
    const int dq = idx & 3, sl = (idx >> 2) & 31, h = idx >> 7;
    const uint4 cv = *(const uint4*)(ctx + ((size_t)(b * 8 + h) * S_ + s0 + sl) * HD_ + dq * 8);
    const int t = sl >> 4, rm = sl & 15;
    const int qds = dq ^ (rm & 3);
    *(uint4*)(XnF + (((t * 8 + h) * 64 + qds * 16 + rm) << 3)) = cv;
  }
  __syncthreads();

  const int lsw = (quad ^ (lr & 3)) * 16 + lr;
  short8 Af[2][8];
#pragma unroll
  for (int mt = 0; mt < 2; ++mt)
#pragma unroll
    for (int c = 0; c < 8; ++c)
      Af[mt][c] = *(const short8*)(XnF + (((mt * 8 + c) * 64 + lsw) << 3));

  short8 Bf[2][8];
#pragma unroll
  for (int c = 0; c < 8; ++c)
    Bf[0][c] = loadBfrag<F32>(wo, (w * 4) * 16 + lr, c * 32 + quad * 8, 256);

#pragma unroll
  for (int nt = 0; nt < 4; ++nt) {
    const int cb = nt & 1;
    if (nt < 3) {
#pragma unroll
      for (int c = 0; c < 8; ++c)
        Bf[cb ^ 1][c] = loadBfrag<F32>(wo, (w * 4 + nt + 1) * 16 + lr, c * 32 + quad * 8, 256);
    }
    const int n0 = (w * 4 + nt) * 16;
    f32x4 a0 = {0.f,0.f,0.f,0.f}, a1 = {0.f,0.f,0.f,0.f};
#pragma unroll
    for (int c = 0; c < 8; ++c) {
      a0 = mfma16(Af[0][c], Bf[cb][c], a0);
      a1 = mfma16(Af[1][c], Bf[cb][c], a1);
    }
#pragma unroll
    for (int m = 0; m < 2; ++m) {
      const f32x4 acc = m ? a1 : a0;
#pragma unroll
      for (int i = 0; i < 4; ++i)
        OutB[(m * 16 + quad * 4 + i) * 264 + n0 + lr] = f2b(acc[i]);
    }
  }
  __syncthreads();

  const int r  = tid >> 3;
  const int c8 = (tid & 7) * 4;
#pragma unroll
  for (int j8 = 0; j8 < 4; ++j8) {
    float xv[8]; load8<F32>(xin, (row0 + r) * 32 + c8 + j8, xv);
    float pv[8]; unp8(*(const uint4*)(OutB + r * 264 + (c8 + j8) * 8), pv);
    float ov[8];
#pragma unroll
    for (int j = 0; j < 8; ++j) ov[j] = (pv[j] + xv[j]) * 0.70710678f;
    store8<F32>(out, (row0 + r) * 32 + c8 + j8, ov);
  }
}

__global__ __launch_bounds__(256, 2) void proj_mfma(
    const u16* __restrict__ ctx, const void* __restrict__ xin,
    const void* __restrict__ wo, void* __restrict__ out)
{
  __shared__ __align__(16) u16 XnF[2 * 8 * 64 * 8];   // 16 KB
  __shared__ __align__(16) u16 OutB[32 * 264];        // 16.5 KB
  if (sniff_mode(xin) == 0) proj_body<0>(ctx, xin, wo, out, XnF, OutB);
  else                      proj_body<1>(ctx, xin, wo, out, XnF, OutB);
}

// ============================================================
extern "C" void kernel_launch(void* const* d_in, const int* in_sizes, int n_in,
                              void* d_out, int out_size, void* d_ws, size_t ws_size,
                              hipStream_t stream)
{
  const void* xin   = d_in[0];
  const void* rmask = d_in[1];
  const void* wi    = d_in[2];
  const void* wo    = d_in[3];
  const void* gam   = d_in[4];
  const void* bet   = d_in[5];

  u16* q   = (u16*)d_ws;                   // [256][512][32] bf16 (8 MB)
  u16* k   = q + 4194304;
  u16* vt  = k + 4194304;                  // sigma-permuted V (8 MB)
  u16* cxb = vt + 4194304;                 // ctx [bh][s][hd] bf16 (8 MB)

  ln_qkv_mfma<<<512,  256, 0, stream>>>(xin, rmask, wi, gam, bet, q, k, vt);
  attn_mfma  <<<1024, 256, 0, stream>>>(q, k, vt, cxb);
  proj_mfma  <<<512,  256, 0, stream>>>(cxb, xin, wo, d_out);
}